// Round 14
// baseline (6273.055 us; speedup 1.0000x reference)
//
#include <hip/hip_runtime.h>

#define NB 32
#define T 256
#define NS 64
#define NC 32
#define NSC 96

typedef short bf16x8 __attribute__((ext_vector_type(8)));
typedef float f32x4  __attribute__((ext_vector_type(4)));

#define COMP(v,i) ((i)==0?(v).x:((i)==1?(v).y:((i)==2?(v).z:(v).w)))

static __device__ __forceinline__ float dot4(float4 a, float4 b){
    return fmaf(a.x,b.x, fmaf(a.y,b.y, fmaf(a.z,b.z, a.w*b.w)));
}
static __device__ __forceinline__ unsigned short f2bf(float x){
    unsigned int u = __float_as_uint(x);
    u += 0x7FFFu + ((u >> 16) & 1u);
    return (unsigned short)(u >> 16);
}
static __device__ __forceinline__ float bf2f(unsigned short h){
    return __uint_as_float(((unsigned int)h) << 16);
}

// Static device-global workspace; fully rewritten every call -> deterministic.
__device__ __align__(16) float g_KtG[(size_t)NB*T*NS*NC];   // [b][t][i][u], Kt[i][u]=K[u][i]
__device__ __align__(16) float g_kkG[(size_t)NB*T*NC];      // [b][t][u]

#define BROW 72   // bf16 row stride for 64-wide tiles (144B)
#define SR32 36   // bf16 row stride for 32-wide tiles (72B)

__device__ __forceinline__ void p2geom(int tix, int& i0, int& j0, int& osel){
    if (tix < 16)      { i0 = (tix & 3)*16;              j0 = (tix >> 2)*16;        osel = 0; }
    else if (tix < 24) { const int q = tix-16; i0 = (q & 3)*16;  j0 = 64 + (q >> 2)*16; osel = 1; }
    else               { const int q = tix-24; i0 = 64 + (q & 1)*16; j0 = 64 + (q >> 1)*16; osel = 2; }
}

// P1 tile: W tile = (V*F) tile via MFMA, stored transposed as bf16 hi/lo (Wt[j][s])
#define P1TILE(tix) { \
    const int s0 = ((tix) & 3) * 16, j0 = ((tix) >> 2) * 16; \
    f32x4 c = {0.f, 0.f, 0.f, 0.f}; \
    _Pragma("unroll") \
    for (int kc = 0; kc < 2; ++kc) { \
        const int ch = (kc*4 + lk) * 8; \
        const bf16x8 ah = *(const bf16x8*)&Vbh[(s0+lm)*BROW + ch]; \
        const bf16x8 al = *(const bf16x8*)&Vbl[(s0+lm)*BROW + ch]; \
        const bf16x8 bh = *(const bf16x8*)&Fth[(j0+lm)*BROW + ch]; \
        const bf16x8 bl = *(const bf16x8*)&Ftl[(j0+lm)*BROW + ch]; \
        c = __builtin_amdgcn_mfma_f32_16x16x32_bf16(ah, bh, c, 0, 0, 0); \
        c = __builtin_amdgcn_mfma_f32_16x16x32_bf16(ah, bl, c, 0, 0, 0); \
        c = __builtin_amdgcn_mfma_f32_16x16x32_bf16(al, bh, c, 0, 0, 0); \
    } \
    ushort4 hv, lv; float rm_; \
    hv.x = f2bf(c[0]); rm_ = c[0] - bf2f(hv.x); lv.x = f2bf(rm_); \
    hv.y = f2bf(c[1]); rm_ = c[1] - bf2f(hv.y); lv.y = f2bf(rm_); \
    hv.z = f2bf(c[2]); rm_ = c[2] - bf2f(hv.z); lv.z = f2bf(rm_); \
    hv.w = f2bf(c[3]); rm_ = c[3] - bf2f(hv.w); lv.w = f2bf(rm_); \
    const int ui = (j0+lm)*BROW + s0 + lk*4; \
    *(ushort4*)&Wth[ui] = hv; \
    *(ushort4*)&Wtl[ui] = lv; \
}

// P2 tile: Qh tile = Qt tile (cin) + (F^T W) tile; scatter to V/Qxu/Quu (+ bf16 copies)
// Quu tiles also stage the 2x2-block-GJ's first pivot rows/cols.
#define P2TILE(cin, tix) { \
    int i0_, j0_, os_; p2geom((tix), i0_, j0_, os_); \
    f32x4 c = cin; \
    _Pragma("unroll") \
    for (int kc = 0; kc < 2; ++kc) { \
        const int ch = (kc*4 + lk) * 8; \
        const bf16x8 ah = *(const bf16x8*)&Fth[(i0_+lm)*BROW + ch]; \
        const bf16x8 al = *(const bf16x8*)&Ftl[(i0_+lm)*BROW + ch]; \
        const bf16x8 bh = *(const bf16x8*)&Wth[(j0_+lm)*BROW + ch]; \
        const bf16x8 bl = *(const bf16x8*)&Wtl[(j0_+lm)*BROW + ch]; \
        c = __builtin_amdgcn_mfma_f32_16x16x32_bf16(ah, bh, c, 0, 0, 0); \
        c = __builtin_amdgcn_mfma_f32_16x16x32_bf16(ah, bl, c, 0, 0, 0); \
        c = __builtin_amdgcn_mfma_f32_16x16x32_bf16(al, bh, c, 0, 0, 0); \
    } \
    _Pragma("unroll") \
    for (int r = 0; r < 4; ++r) { \
        const int i_ = i0_ + lk*4 + r, j_ = j0_ + lm; \
        if (os_ == 0) { V[i_][j_] = c[r]; } \
        else if (os_ == 1) { \
            const int u_ = j_ - 64; \
            Qxu[i_][u_] = c[r]; \
            const unsigned short h_ = f2bf(c[r]); \
            Qxuh[i_*SR32 + u_] = h_; \
            Qxul[i_*SR32 + u_] = f2bf(c[r] - bf2f(h_)); \
        } else { \
            const int wr_ = i_ - 64, u_ = j_ - 64; \
            Maug[wr_][u_] = c[r]; QuuC[wr_][u_] = c[r]; \
            const unsigned short h_ = f2bf(c[r]); \
            Quuh[wr_*SR32 + u_] = h_; \
            Quul[wr_*SR32 + u_] = f2bf(c[r] - bf2f(h_)); \
            if (wr_ < 2) prow2[0][wr_][u_] = c[r]; \
            if (u_ < 2)  pfac2[0][u_][wr_] = c[r]; \
        } \
    } \
}

// ---------------------------------------------------------------------------
// Backward Riccati (policy-evaluation form). All five GEMM phases on matrix
// cores (bf16 hi/lo 3-product split). Sync intervals minimized: 2x2-blocked
// GJ (16 barriers), P3b merged into GJ epilogue, P0 merged into P1 wave 7.
// ---------------------------------------------------------------------------
__global__ __launch_bounds__(512)
void lqr_bwd(const float* __restrict__ Qg_, const float* __restrict__ pg_,
             const float* __restrict__ Ag_, const float* __restrict__ Bg_,
             const float* __restrict__ c1g_, const float* __restrict__ x0g_,
             float* __restrict__ outc)
{
    __shared__ __align__(16) float V[64][68];               // carry V; Qxx between P2 and P6
    __shared__ __align__(16) unsigned short Vbh[64*BROW];   // V bf16 hi/lo (P1-A)
    __shared__ __align__(16) unsigned short Vbl[64*BROW];
    __shared__ __align__(16) unsigned short Fth[96*BROW];   // Ft[j][s]=F[s][j] bf16 hi/lo
    __shared__ __align__(16) unsigned short Ftl[96*BROW];
    __shared__ __align__(16) unsigned short Wth[96*BROW];   // Wt[j][s]=W[s][j] bf16 hi/lo
    __shared__ __align__(16) unsigned short Wtl[96*BROW];
    __shared__ __align__(16) float Qxu[64][36];
    __shared__ __align__(16) float QuuC[32][36];
    __shared__ __align__(16) float Maug[32][68];            // Quu in cols 0:32; Minv written to 32:64
    __shared__ __align__(16) float prow2[2][2][64];         // GJ: 2 pivot rows, dbuf
    __shared__ __align__(16) float pfac2[2][2][32];         // GJ: 2 pivot cols, dbuf
    __shared__ __align__(16) unsigned short Qxuh[64*SR32], Qxul[64*SR32];
    __shared__ __align__(16) unsigned short Kth[64*SR32],  Ktl[64*SR32];
    __shared__ __align__(16) unsigned short Minvh[32*SR32], Minvl[32*SR32];
    __shared__ __align__(16) unsigned short Quuh[32*SR32],  Quul[32*SR32];
    __shared__ __align__(16) unsigned short Rth[64*SR32];
    __shared__ __align__(16) float qh[96];
    __shared__ __align__(16) float gv[64];
    __shared__ __align__(16) float hbuf[32];
    __shared__ __align__(16) float c1l[64];
    __shared__ __align__(16) float vl[64];
    __shared__ __align__(16) float kkl[32];
    __shared__ __align__(16) float x0l[64];
    __shared__ float wAcc;

    const int tid = threadIdx.x;
    const int b   = blockIdx.x;
    const int w   = tid >> 6;        // wave 0..7
    const int lm  = tid & 15;        // fragment row/col
    const int lk  = (tid & 63) >> 4; // fragment k-group 0..3

    const float* Qg = Qg_ + (size_t)b*T*NSC*NSC;
    const float* pg = pg_ + (size_t)b*T*NSC;
    const float* Ag = Ag_ + (size_t)b*NS*NS;
    const float* Bg = Bg_ + (size_t)b*NS*NC;
    float* KtG = g_KtG + (size_t)b*T*NS*NC;
    float* kkG = g_kkG + (size_t)b*T*NC;

    // ---- init: F -> bf16 hi/lo transposed; V = 0 (fp32 + bf16)
    for (int e = tid; e < 96*64; e += 512) {
        const int j = e >> 6, s = e & 63;
        const float x = (j < 64) ? Ag[s*64 + j] : Bg[s*32 + (j-64)];
        const unsigned short h = f2bf(x);
        Fth[j*BROW + s] = h;
        Ftl[j*BROW + s] = f2bf(x - bf2f(h));
    }
    for (int e = tid; e < 64*BROW; e += 512) { Vbh[e] = 0; Vbl[e] = 0; }
    for (int e = tid; e < 64*68; e += 512) ((float*)V)[e] = 0.f;
    if (tid < 64) { c1l[tid] = c1g_[b*64+tid]; vl[tid] = 0.f; x0l[tid] = x0g_[b*64+tid]; }
    if (tid == 0) wAcc = 0.f;
    __syncthreads();

    // GJ thread roles
    const int wq  = tid >> 4;
    const int gjq = tid & 15, gj0 = gjq * 4;

    // P2 tile schedule: waves 0-3: 4 tiles, waves 4-7: 3 tiles (28 total)
    const int p2s = (w < 4) ? w*4 : 16 + (w-4)*3;
    const int p2n = (w < 4) ? 4 : 3;

    for (int t = T-1; t >= 0; --t) {
        const float* Qt = Qg + (size_t)t*NSC*NSC;
        const float* pt = pg + (size_t)t*NSC;

        // ---- Qt prefetch for this wave's P2 tiles (issued early, used in P2)
        f32x4 qt0, qt1, qt2, qt3;
        {
            int i0, j0, os;
            p2geom(p2s+0, i0, j0, os);
            const float* s0p = Qt + (size_t)(i0 + lk*4)*96 + j0 + lm;
            qt0[0]=s0p[0]; qt0[1]=s0p[96]; qt0[2]=s0p[192]; qt0[3]=s0p[288];
            p2geom(p2s+1, i0, j0, os);
            const float* s1p = Qt + (size_t)(i0 + lk*4)*96 + j0 + lm;
            qt1[0]=s1p[0]; qt1[1]=s1p[96]; qt1[2]=s1p[192]; qt1[3]=s1p[288];
            p2geom(p2s+2, i0, j0, os);
            const float* s2p = Qt + (size_t)(i0 + lk*4)*96 + j0 + lm;
            qt2[0]=s2p[0]; qt2[1]=s2p[96]; qt2[2]=s2p[192]; qt2[3]=s2p[288];
            if (p2n == 4) {
                p2geom(p2s+3, i0, j0, os);
                const float* s3p = Qt + (size_t)(i0 + lk*4)*96 + j0 + lm;
                qt3[0]=s3p[0]; qt3[1]=s3p[96]; qt3[2]=s3p[192]; qt3[3]=s3p[288];
            } else { qt3 = qt0; }
        }

        // ---- P1 (MFMA): W = V*F, 24 tiles over waves 0-6.
        //      Wave 7 (R10/R11-verified block): gv = V*c1 + v, wAcc c1-term,
        //      qh = pt + F'gv via bf16 Ft rows. All reads (V, Fth/Ftl) are
        //      stable during P1; qh/gv/wAcc consumed only after P2.
        if (w < 7) {
            const int st = (w < 3) ? w*4 : 12 + (w-3)*3;
            P1TILE(st+0)
            P1TILE(st+1)
            P1TILE(st+2)
            if (w < 3) { P1TILE(st+3) }
        } else {
            const int ll = tid & 63;
            float d = 0.f;
            #pragma unroll
            for (int k4 = 0; k4 < 16; ++k4)
                d += dot4(*(const float4*)&V[ll][k4*4], *(const float4*)&c1l[k4*4]);
            gv[ll] = d + vl[ll];
            float ps = c1l[ll]*(0.5f*d + vl[ll]);
            ps += __shfl_xor(ps,32); ps += __shfl_xor(ps,16); ps += __shfl_xor(ps,8);
            ps += __shfl_xor(ps,4);  ps += __shfl_xor(ps,2);  ps += __shfl_xor(ps,1);
            if (ll == 0) wAcc += ps;
            float q0 = pt[ll];
            float q1 = (ll < 32) ? pt[64+ll] : 0.f;
            #pragma unroll
            for (int cg = 0; cg < 8; ++cg) {
                const bf16x8 h1 = *(const bf16x8*)&Fth[ll*BROW + cg*8];
                const bf16x8 l1 = *(const bf16x8*)&Ftl[ll*BROW + cg*8];
                bf16x8 h2 = h1, l2 = l1;
                if (ll < 32) {
                    h2 = *(const bf16x8*)&Fth[(64+ll)*BROW + cg*8];
                    l2 = *(const bf16x8*)&Ftl[(64+ll)*BROW + cg*8];
                }
                #pragma unroll
                for (int i = 0; i < 8; ++i) {
                    const float gs = gv[cg*8 + i];
                    q0 = fmaf(bf2f((unsigned short)h1[i]) + bf2f((unsigned short)l1[i]), gs, q0);
                    if (ll < 32)
                        q1 = fmaf(bf2f((unsigned short)h2[i]) + bf2f((unsigned short)l2[i]), gs, q1);
                }
            }
            qh[ll] = q0;
            if (ll < 32) qh[64+ll] = q1;
        }
        __syncthreads();

        // ---- P2 (MFMA): Qh = Qt + F'W; 28 tiles over all 8 waves.
        //      Quu tiles stage GJ block-0 pivot rows/cols; identity half below.
        P2TILE(qt0, p2s+0)
        P2TILE(qt1, p2s+1)
        P2TILE(qt2, p2s+2)
        if (p2n == 4) { P2TILE(qt3, p2s+3) }
        if (tid < 64) {   // identity half of GJ block-0 pivot rows
            const int rr = tid >> 5, cc2 = tid & 31;
            prow2[0][rr][32 + cc2] = (cc2 == rr) ? 1.f : 0.f;
        }
        __syncthreads();

        // ---- P3: 2x2-blocked Gauss-Jordan of Quu, matrix-in-registers,
        //      1 barrier per 2 pivots (16 total). Exact block elimination.
        {
            float4 m;
            if (gjq < 8) m = *(const float4*)&Maug[wq][gj0];
            else {
                const int base = gj0 - 32;
                m.x = (base+0==wq)?1.f:0.f; m.y = (base+1==wq)?1.f:0.f;
                m.z = (base+2==wq)?1.f:0.f; m.w = (base+3==wq)?1.f:0.f;
            }
            #pragma unroll
            for (int blk = 0; blk < 16; ++blk) {
                const int k = blk*2;
                const int par = blk & 1, nxt = par ^ 1;
                const float a  = prow2[par][0][k],  bq = prow2[par][0][k+1];
                const float cc = prow2[par][1][k],  d  = prow2[par][1][k+1];
                const float idet = 1.0f / fmaf(a, d, -bq*cc);
                const float4 r0 = *(const float4*)&prow2[par][0][gj0];
                const float4 r1 = *(const float4*)&prow2[par][1][gj0];
                if (wq == k) {
                    m.x = (d*r0.x - bq*r1.x)*idet;
                    m.y = (d*r0.y - bq*r1.y)*idet;
                    m.z = (d*r0.z - bq*r1.z)*idet;
                    m.w = (d*r0.w - bq*r1.w)*idet;
                } else if (wq == k+1) {
                    m.x = (a*r1.x - cc*r0.x)*idet;
                    m.y = (a*r1.y - cc*r0.y)*idet;
                    m.z = (a*r1.z - cc*r0.z)*idet;
                    m.w = (a*r1.w - cc*r0.w)*idet;
                } else {
                    const float C0 = pfac2[par][0][wq], C1 = pfac2[par][1][wq];
                    const float E0 = (C0*d - C1*cc)*idet;
                    const float E1 = (C1*a - C0*bq)*idet;
                    m.x = fmaf(-E0, r0.x, fmaf(-E1, r1.x, m.x));
                    m.y = fmaf(-E0, r0.y, fmaf(-E1, r1.y, m.y));
                    m.z = fmaf(-E0, r0.z, fmaf(-E1, r1.z, m.z));
                    m.w = fmaf(-E0, r0.w, fmaf(-E1, r1.w, m.w));
                }
                if (blk < 15) {
                    if (wq == k+2)      *(float4*)&prow2[nxt][0][gj0] = m;
                    else if (wq == k+3) *(float4*)&prow2[nxt][1][gj0] = m;
                    if (gjq == ((k+2) >> 2)) {
                        pfac2[nxt][0][wq] = COMP(m, (k+2)&3);
                        pfac2[nxt][1][wq] = COMP(m, (k+3)&3);
                    }
                }
                __syncthreads();
            }
            // epilogue (P3b merged): Minv cols live in gjq>=8 registers
            if (gjq >= 8) {
                *(float4*)&Maug[wq][gj0] = m;   // fp32 Minv at cols 32:64 (kk tail)
                ushort4 hv, lv;
                hv.x = f2bf(m.x); lv.x = f2bf(m.x - bf2f(hv.x));
                hv.y = f2bf(m.y); lv.y = f2bf(m.y - bf2f(hv.y));
                hv.z = f2bf(m.z); lv.z = f2bf(m.z - bf2f(hv.z));
                hv.w = f2bf(m.w); lv.w = f2bf(m.w - bf2f(hv.w));
                const int u_ = gj0 - 32;
                *(ushort4*)&Minvh[wq*SR32 + u_] = hv;
                *(ushort4*)&Minvl[wq*SR32 + u_] = lv;
            }
            __syncthreads();
        }

        // ---- P4 (MFMA): K = -Qxu*Minv^T; 8 tiles, 1/wave. kk = -Minv*qu (tail).
        {
            const int i0 = (w & 3)*16, u0 = (w >> 2)*16;
            const int ch = lk*8;
            f32x4 c = {0.f,0.f,0.f,0.f};
            const bf16x8 ah = *(const bf16x8*)&Qxuh[(i0+lm)*SR32 + ch];
            const bf16x8 al = *(const bf16x8*)&Qxul[(i0+lm)*SR32 + ch];
            const bf16x8 bh = *(const bf16x8*)&Minvh[(u0+lm)*SR32 + ch];
            const bf16x8 bl = *(const bf16x8*)&Minvl[(u0+lm)*SR32 + ch];
            c = __builtin_amdgcn_mfma_f32_16x16x32_bf16(ah, bh, c, 0, 0, 0);
            c = __builtin_amdgcn_mfma_f32_16x16x32_bf16(ah, bl, c, 0, 0, 0);
            c = __builtin_amdgcn_mfma_f32_16x16x32_bf16(al, bh, c, 0, 0, 0);
            #pragma unroll
            for (int r = 0; r < 4; ++r) {
                const int i_ = i0 + lk*4 + r, u_ = u0 + lm;
                const float kv = -c[r];
                KtG[(size_t)t*2048 + i_*32 + u_] = kv;
                const unsigned short h = f2bf(kv);
                Kth[i_*SR32 + u_] = h;
                Ktl[i_*SR32 + u_] = f2bf(kv - bf2f(h));
            }
            if (tid < 32) {
                float ka = 0.f;
                #pragma unroll
                for (int w4 = 0; w4 < 8; ++w4)
                    ka -= dot4(*(const float4*)&Maug[tid][32+w4*4], *(const float4*)&qh[64+w4*4]);
                kkl[tid] = ka;
                kkG[t*32 + tid] = ka;
            }
        }
        __syncthreads();

        // ---- P5 (MFMA): Rt[j][u] = Qxu[j][u] + (Kt*Quu)[j][u]; 8 tiles, hi-only out.
        //      hbuf = qu + Quu*kk (tail).
        {
            const int j0 = (w & 3)*16, u0 = (w >> 2)*16;
            const int ch = lk*8;
            f32x4 c;
            #pragma unroll
            for (int r = 0; r < 4; ++r) c[r] = Qxu[j0 + lk*4 + r][u0 + lm];
            const bf16x8 ah = *(const bf16x8*)&Kth[(j0+lm)*SR32 + ch];
            const bf16x8 al = *(const bf16x8*)&Ktl[(j0+lm)*SR32 + ch];
            const bf16x8 bh = *(const bf16x8*)&Quuh[(u0+lm)*SR32 + ch];
            const bf16x8 bl = *(const bf16x8*)&Quul[(u0+lm)*SR32 + ch];
            c = __builtin_amdgcn_mfma_f32_16x16x32_bf16(ah, bh, c, 0, 0, 0);
            c = __builtin_amdgcn_mfma_f32_16x16x32_bf16(ah, bl, c, 0, 0, 0);
            c = __builtin_amdgcn_mfma_f32_16x16x32_bf16(al, bh, c, 0, 0, 0);
            #pragma unroll
            for (int r = 0; r < 4; ++r)
                Rth[(j0 + lk*4 + r)*SR32 + u0 + lm] = f2bf(c[r]);
            if (tid < 32) {
                float h = qh[64+tid];
                #pragma unroll
                for (int w4 = 0; w4 < 8; ++w4)
                    h += dot4(*(const float4*)&QuuC[tid][w4*4], *(const float4*)&kkl[w4*4]);
                hbuf[tid] = h;
            }
        }
        __syncthreads();

        // ---- P6 (MFMA): V <- Qxx + Qxu*K + K'Rt; 16 tiles, 2/wave, in-place V.
        #pragma unroll
        for (int half = 0; half < 2; ++half) {
            const int tx = w + half*8;
            const int i0 = (tx & 3)*16, j0 = (tx >> 2)*16;
            const int ch = lk*8;
            f32x4 c;
            #pragma unroll
            for (int r = 0; r < 4; ++r) c[r] = V[i0 + lk*4 + r][j0 + lm];
            const bf16x8 ah  = *(const bf16x8*)&Qxuh[(i0+lm)*SR32 + ch];
            const bf16x8 al  = *(const bf16x8*)&Qxul[(i0+lm)*SR32 + ch];
            const bf16x8 bh  = *(const bf16x8*)&Kth[(j0+lm)*SR32 + ch];
            const bf16x8 bl  = *(const bf16x8*)&Ktl[(j0+lm)*SR32 + ch];
            const bf16x8 a2h = *(const bf16x8*)&Kth[(i0+lm)*SR32 + ch];
            const bf16x8 b2h = *(const bf16x8*)&Rth[(j0+lm)*SR32 + ch];
            c = __builtin_amdgcn_mfma_f32_16x16x32_bf16(ah,  bh,  c, 0, 0, 0);
            c = __builtin_amdgcn_mfma_f32_16x16x32_bf16(ah,  bl,  c, 0, 0, 0);
            c = __builtin_amdgcn_mfma_f32_16x16x32_bf16(al,  bh,  c, 0, 0, 0);
            c = __builtin_amdgcn_mfma_f32_16x16x32_bf16(a2h, b2h, c, 0, 0, 0);
            #pragma unroll
            for (int r = 0; r < 4; ++r) V[i0 + lk*4 + r][j0 + lm] = c[r];
        }
        __syncthreads();

        // ---- symmetrize V + bf16 convert (256 thr); vn (256-319); wAcc (320-351)
        if (tid < 256) {
            const int a = tid >> 4, bq = tid & 15;
            if (a < bq) {
                float4 t1[4], t2[4];
                #pragma unroll
                for (int r = 0; r < 4; ++r) {
                    t1[r] = *(const float4*)&V[4*a+r][4*bq];
                    t2[r] = *(const float4*)&V[4*bq+r][4*a];
                }
                #pragma unroll
                for (int r = 0; r < 4; ++r) {
                    float4 o, p;
                    o.x = 0.5f*(COMP(t1[r],0)+COMP(t2[0],r));
                    o.y = 0.5f*(COMP(t1[r],1)+COMP(t2[1],r));
                    o.z = 0.5f*(COMP(t1[r],2)+COMP(t2[2],r));
                    o.w = 0.5f*(COMP(t1[r],3)+COMP(t2[3],r));
                    p.x = 0.5f*(COMP(t2[r],0)+COMP(t1[0],r));
                    p.y = 0.5f*(COMP(t2[r],1)+COMP(t1[1],r));
                    p.z = 0.5f*(COMP(t2[r],2)+COMP(t1[2],r));
                    p.w = 0.5f*(COMP(t2[r],3)+COMP(t1[3],r));
                    *(float4*)&V[4*a+r][4*bq] = o;
                    *(float4*)&V[4*bq+r][4*a] = p;
                    ushort4 oh, ol, ph, pl;
                    oh.x=f2bf(o.x); ol.x=f2bf(o.x-bf2f(oh.x));
                    oh.y=f2bf(o.y); ol.y=f2bf(o.y-bf2f(oh.y));
                    oh.z=f2bf(o.z); ol.z=f2bf(o.z-bf2f(oh.z));
                    oh.w=f2bf(o.w); ol.w=f2bf(o.w-bf2f(oh.w));
                    ph.x=f2bf(p.x); pl.x=f2bf(p.x-bf2f(ph.x));
                    ph.y=f2bf(p.y); pl.y=f2bf(p.y-bf2f(ph.y));
                    ph.z=f2bf(p.z); pl.z=f2bf(p.z-bf2f(ph.z));
                    ph.w=f2bf(p.w); pl.w=f2bf(p.w-bf2f(ph.w));
                    *(ushort4*)&Vbh[(4*a+r)*BROW + 4*bq] = oh;
                    *(ushort4*)&Vbl[(4*a+r)*BROW + 4*bq] = ol;
                    *(ushort4*)&Vbh[(4*bq+r)*BROW + 4*a] = ph;
                    *(ushort4*)&Vbl[(4*bq+r)*BROW + 4*a] = pl;
                }
            } else if (a == bq) {
                float4 t1[4];
                #pragma unroll
                for (int r = 0; r < 4; ++r) t1[r] = *(const float4*)&V[4*a+r][4*a];
                #pragma unroll
                for (int r = 0; r < 4; ++r) {
                    float4 o;
                    o.x = 0.5f*(COMP(t1[r],0)+COMP(t1[0],r));
                    o.y = 0.5f*(COMP(t1[r],1)+COMP(t1[1],r));
                    o.z = 0.5f*(COMP(t1[r],2)+COMP(t1[2],r));
                    o.w = 0.5f*(COMP(t1[r],3)+COMP(t1[3],r));
                    *(float4*)&V[4*a+r][4*a] = o;
                    ushort4 oh, ol;
                    oh.x=f2bf(o.x); ol.x=f2bf(o.x-bf2f(oh.x));
                    oh.y=f2bf(o.y); ol.y=f2bf(o.y-bf2f(oh.y));
                    oh.z=f2bf(o.z); ol.z=f2bf(o.z-bf2f(oh.z));
                    oh.w=f2bf(o.w); ol.w=f2bf(o.w-bf2f(oh.w));
                    *(ushort4*)&Vbh[(4*a+r)*BROW + 4*a] = oh;
                    *(ushort4*)&Vbl[(4*a+r)*BROW + 4*a] = ol;
                }
            }
        } else if (tid < 320) {
            const int l = tid - 256;
            float vv = qh[l];
            #pragma unroll
            for (int u4 = 0; u4 < 8; ++u4)
                vv += dot4(*(const float4*)&Qxu[l][u4*4], *(const float4*)&kkl[u4*4]);
            #pragma unroll
            for (int cg = 0; cg < 4; ++cg) {
                const bf16x8 h8 = *(const bf16x8*)&Kth[l*SR32 + cg*8];
                const bf16x8 l8 = *(const bf16x8*)&Ktl[l*SR32 + cg*8];
                #pragma unroll
                for (int i = 0; i < 8; ++i)
                    vv = fmaf(bf2f((unsigned short)h8[i]) + bf2f((unsigned short)l8[i]),
                              hbuf[cg*8+i], vv);
            }
            vl[l] = vv;
        } else if (tid < 352) {
            const int u = tid - 320;
            float r = kkl[u]*(hbuf[u] + qh[64+u]);
            r += __shfl_xor(r,16); r += __shfl_xor(r,8); r += __shfl_xor(r,4);
            r += __shfl_xor(r,2);  r += __shfl_xor(r,1);
            if (u == 0) wAcc += 0.5f*r;
        }
        __syncthreads();
    }

    // ---- cost[b] = wAcc + 0.5*x0'V0 x0 + v0'x0
    if (tid < 64) {
        float rd = 0.f;
        #pragma unroll
        for (int k4 = 0; k4 < 16; ++k4)
            rd += dot4(*(const float4*)&V[tid][k4*4], *(const float4*)&x0l[k4*4]);
        float ps = x0l[tid]*(0.5f*rd + vl[tid]);
        ps += __shfl_xor(ps,32); ps += __shfl_xor(ps,16); ps += __shfl_xor(ps,8);
        ps += __shfl_xor(ps,4);  ps += __shfl_xor(ps,2);  ps += __shfl_xor(ps,1);
        if (tid == 0) outc[b] = wAcc + ps;
    }
}

// ---------------------------------------------------------------------------
// Forward rollout (unchanged): 256 threads per batch; split dot products
// with shfl_xor reduction; K(t+1) reg-prefetched.
// ---------------------------------------------------------------------------
__global__ __launch_bounds__(256)
void lqr_fwd(const float* __restrict__ Ag_, const float* __restrict__ Bg_,
             const float* __restrict__ c1g_, const float* __restrict__ x0g_,
             float* __restrict__ outx, float* __restrict__ outu)
{
    __shared__ __align__(16) float At[64][68];
    __shared__ __align__(16) float Bt[32][68];
    __shared__ __align__(16) float KtL[64][36];
    __shared__ float xl[64], ul[32], cl[64], kl[32], xnb[64];

    const int tid = threadIdx.x;
    const int b = blockIdx.x;

    const float* KtG = g_KtG + (size_t)b*T*NS*NC;
    const float* kkG = g_kkG + (size_t)b*T*NC;

    for (int e = tid; e < NS*NS; e += 256) At[e&63][e>>6] = Ag_[(size_t)b*4096 + e];
    for (int e = tid; e < NS*NC; e += 256) Bt[e&31][e>>5] = Bg_[(size_t)b*2048 + e];
    if (tid < 64) { xl[tid] = x0g_[b*64 + tid]; cl[tid] = c1g_[b*64 + tid]; }

    {
        const int i1 = tid*4, i2 = 1024 + tid*4;
        const float4 a = *(const float4*)&KtG[i1];
        const float4 c = *(const float4*)&KtG[i2];
        *(float4*)&KtL[i1>>5][i1&31] = a;
        *(float4*)&KtL[i2>>5][i2&31] = c;
        if (tid < 32) kl[tid] = kkG[tid];
    }
    __syncthreads();

    float4 g0, g1; float kn = 0.f;
    for (int t = 0; t < T; ++t) {
        if (t+1 < T) {
            g0 = *(const float4*)&KtG[(size_t)(t+1)*2048 + tid*4];
            g1 = *(const float4*)&KtG[(size_t)(t+1)*2048 + 1024 + tid*4];
            if (tid < 32) kn = kkG[(t+1)*32 + tid];
        }

        if (tid < 64) outx[((size_t)b*T + t)*64 + tid] = xl[tid];
        if (tid < 128) {
            const int u = tid >> 2, sp = tid & 3, s0 = sp*16;
            float r = 0.f;
            #pragma unroll
            for (int i = 0; i < 16; ++i) r = fmaf(KtL[s0+i][u], xl[s0+i], r);
            r += __shfl_xor(r, 1); r += __shfl_xor(r, 2);
            if (sp == 0) {
                const float uu = r + kl[u];
                ul[u] = uu;
                outu[((size_t)b*T + t)*32 + u] = uu;
            }
        }
        __syncthreads();

        {
            const int o = tid >> 2, sp = tid & 3;
            float r = 0.f;
            #pragma unroll
            for (int i = 0; i < 16; ++i) { const int j = sp*16 + i; r = fmaf(At[j][o], xl[j], r); }
            #pragma unroll
            for (int i = 0; i < 8; ++i)  { const int w2 = sp*8 + i; r = fmaf(Bt[w2][o], ul[w2], r); }
            r += __shfl_xor(r, 1); r += __shfl_xor(r, 2);
            if (sp == 0) xnb[o] = r + cl[o];
        }
        __syncthreads();

        if (tid < 64) xl[tid] = xnb[tid];
        if (t+1 < T) {
            const int i1 = tid*4, i2 = 1024 + tid*4;
            *(float4*)&KtL[i1>>5][i1&31] = g0;
            *(float4*)&KtL[i2>>5][i2&31] = g1;
            if (tid < 32) kl[tid] = kn;
        }
        __syncthreads();
    }
}

// ---------------------------------------------------------------------------
extern "C" void kernel_launch(void* const* d_in, const int* in_sizes, int n_in,
                              void* d_out, int out_size, void* d_ws, size_t ws_size,
                              hipStream_t stream)
{
    const float* Q  = (const float*)d_in[0];
    const float* p  = (const float*)d_in[1];
    const float* A  = (const float*)d_in[2];
    const float* B  = (const float*)d_in[3];
    const float* c1 = (const float*)d_in[4];
    const float* x0 = (const float*)d_in[5];

    float* outx = (float*)d_out;                       // (NB,T,NS)
    float* outu = outx + (size_t)NB*T*NS;              // (NB,T,NC)
    float* outc = outu + (size_t)NB*T*NC;              // (NB,)

    lqr_bwd<<<NB, 512, 0, stream>>>(Q, p, A, B, c1, x0, outc);
    lqr_fwd<<<NB, 256, 0, stream>>>(A, B, c1, x0, outx, outu);
}

// Round 15
// 4551.512 us; speedup vs baseline: 1.3782x; 1.3782x over previous
//
#include <hip/hip_runtime.h>

#define NB 32
#define T 256
#define NS 64
#define NC 32
#define NSC 96

typedef short bf16x8 __attribute__((ext_vector_type(8)));
typedef float f32x4  __attribute__((ext_vector_type(4)));

#define COMP(v,i) ((i)==0?(v).x:((i)==1?(v).y:((i)==2?(v).z:(v).w)))

static __device__ __forceinline__ float dot4(float4 a, float4 b){
    return fmaf(a.x,b.x, fmaf(a.y,b.y, fmaf(a.z,b.z, a.w*b.w)));
}
static __device__ __forceinline__ unsigned short f2bf(float x){
    unsigned int u = __float_as_uint(x);
    u += 0x7FFFu + ((u >> 16) & 1u);
    return (unsigned short)(u >> 16);
}
static __device__ __forceinline__ float bf2f(unsigned short h){
    return __uint_as_float(((unsigned int)h) << 16);
}

// Static device-global workspace; fully rewritten every call -> deterministic.
__device__ __align__(16) float g_KtG[(size_t)NB*T*NS*NC];   // [b][t][i][u], Kt[i][u]=K[u][i]
__device__ __align__(16) float g_kkG[(size_t)NB*T*NC];      // [b][t][u]

#define BROW 72   // bf16 row stride for 64-wide tiles (144B)
#define SR32 36   // bf16 row stride for 32-wide tiles (72B)

__device__ __forceinline__ void p2geom(int tix, int& i0, int& j0, int& osel){
    if (tix < 16)      { i0 = (tix & 3)*16;              j0 = (tix >> 2)*16;        osel = 0; }
    else if (tix < 24) { const int q = tix-16; i0 = (q & 3)*16;  j0 = 64 + (q >> 2)*16; osel = 1; }
    else               { const int q = tix-24; i0 = 64 + (q & 1)*16; j0 = 64 + (q >> 1)*16; osel = 2; }
}

// P1 tile: W tile = (V*F) tile via MFMA, stored transposed as bf16 hi/lo (Wt[j][s])
#define P1TILE(tix) { \
    const int s0 = ((tix) & 3) * 16, j0 = ((tix) >> 2) * 16; \
    f32x4 c = {0.f, 0.f, 0.f, 0.f}; \
    _Pragma("unroll") \
    for (int kc = 0; kc < 2; ++kc) { \
        const int ch = (kc*4 + lk) * 8; \
        const bf16x8 ah = *(const bf16x8*)&Vbh[(s0+lm)*BROW + ch]; \
        const bf16x8 al = *(const bf16x8*)&Vbl[(s0+lm)*BROW + ch]; \
        const bf16x8 bh = *(const bf16x8*)&Fth[(j0+lm)*BROW + ch]; \
        const bf16x8 bl = *(const bf16x8*)&Ftl[(j0+lm)*BROW + ch]; \
        c = __builtin_amdgcn_mfma_f32_16x16x32_bf16(ah, bh, c, 0, 0, 0); \
        c = __builtin_amdgcn_mfma_f32_16x16x32_bf16(ah, bl, c, 0, 0, 0); \
        c = __builtin_amdgcn_mfma_f32_16x16x32_bf16(al, bh, c, 0, 0, 0); \
    } \
    ushort4 hv, lv; float rm_; \
    hv.x = f2bf(c[0]); rm_ = c[0] - bf2f(hv.x); lv.x = f2bf(rm_); \
    hv.y = f2bf(c[1]); rm_ = c[1] - bf2f(hv.y); lv.y = f2bf(rm_); \
    hv.z = f2bf(c[2]); rm_ = c[2] - bf2f(hv.z); lv.z = f2bf(rm_); \
    hv.w = f2bf(c[3]); rm_ = c[3] - bf2f(hv.w); lv.w = f2bf(rm_); \
    const int ui = (j0+lm)*BROW + s0 + lk*4; \
    *(ushort4*)&Wth[ui] = hv; \
    *(ushort4*)&Wtl[ui] = lv; \
}

// P2 tile: Qh tile = Qt tile (cin) + (F^T W) tile; scatter to V/Qxu/Quu (+ bf16 copies)
// Quu tiles also stage the 2x2-block-GJ's first pivot rows/cols.
#define P2TILE(cin, tix) { \
    int i0_, j0_, os_; p2geom((tix), i0_, j0_, os_); \
    f32x4 c = cin; \
    _Pragma("unroll") \
    for (int kc = 0; kc < 2; ++kc) { \
        const int ch = (kc*4 + lk) * 8; \
        const bf16x8 ah = *(const bf16x8*)&Fth[(i0_+lm)*BROW + ch]; \
        const bf16x8 al = *(const bf16x8*)&Ftl[(i0_+lm)*BROW + ch]; \
        const bf16x8 bh = *(const bf16x8*)&Wth[(j0_+lm)*BROW + ch]; \
        const bf16x8 bl = *(const bf16x8*)&Wtl[(j0_+lm)*BROW + ch]; \
        c = __builtin_amdgcn_mfma_f32_16x16x32_bf16(ah, bh, c, 0, 0, 0); \
        c = __builtin_amdgcn_mfma_f32_16x16x32_bf16(ah, bl, c, 0, 0, 0); \
        c = __builtin_amdgcn_mfma_f32_16x16x32_bf16(al, bh, c, 0, 0, 0); \
    } \
    _Pragma("unroll") \
    for (int r = 0; r < 4; ++r) { \
        const int i_ = i0_ + lk*4 + r, j_ = j0_ + lm; \
        if (os_ == 0) { V[i_][j_] = c[r]; } \
        else if (os_ == 1) { \
            const int u_ = j_ - 64; \
            Qxu[i_][u_] = c[r]; \
            const unsigned short h_ = f2bf(c[r]); \
            Qxuh[i_*SR32 + u_] = h_; \
            Qxul[i_*SR32 + u_] = f2bf(c[r] - bf2f(h_)); \
        } else { \
            const int wr_ = i_ - 64, u_ = j_ - 64; \
            Maug[wr_][u_] = c[r]; QuuC[wr_][u_] = c[r]; \
            const unsigned short h_ = f2bf(c[r]); \
            Quuh[wr_*SR32 + u_] = h_; \
            Quul[wr_*SR32 + u_] = f2bf(c[r] - bf2f(h_)); \
            if (wr_ < 2) prow2[0][wr_][u_] = c[r]; \
            if (u_ < 2)  pfac2[0][u_][wr_] = c[r]; \
        } \
    } \
}

// ---------------------------------------------------------------------------
// Backward Riccati (policy-evaluation form). All five GEMM phases on matrix
// cores (bf16 hi/lo 3-product split). R13 structure + 2x2-blocked GJ
// (16 barriers) with Minv->bf16 merged into the GJ epilogue.
// ---------------------------------------------------------------------------
__global__ __launch_bounds__(512)
void lqr_bwd(const float* __restrict__ Qg_, const float* __restrict__ pg_,
             const float* __restrict__ Ag_, const float* __restrict__ Bg_,
             const float* __restrict__ c1g_, const float* __restrict__ x0g_,
             float* __restrict__ outc)
{
    __shared__ __align__(16) float V[64][68];               // carry V; Qxx between P2 and P6
    __shared__ __align__(16) unsigned short Vbh[64*BROW];   // V bf16 hi/lo (P1-A)
    __shared__ __align__(16) unsigned short Vbl[64*BROW];
    __shared__ __align__(16) unsigned short Fth[96*BROW];   // Ft[j][s]=F[s][j] bf16 hi/lo
    __shared__ __align__(16) unsigned short Ftl[96*BROW];
    __shared__ __align__(16) unsigned short Wth[96*BROW];   // Wt[j][s]=W[s][j] bf16 hi/lo
    __shared__ __align__(16) unsigned short Wtl[96*BROW];
    __shared__ __align__(16) float Qxu[64][36];
    __shared__ __align__(16) float QuuC[32][36];
    __shared__ __align__(16) float Maug[32][68];            // Quu cols 0:32; Minv -> 32:64
    __shared__ __align__(16) float prow2[2][2][64];         // GJ: 2 pivot rows, dbuf
    __shared__ __align__(16) float pfac2[2][2][32];         // GJ: 2 pivot cols, dbuf
    __shared__ __align__(16) unsigned short Qxuh[64*SR32], Qxul[64*SR32];
    __shared__ __align__(16) unsigned short Kth[64*SR32],  Ktl[64*SR32];
    __shared__ __align__(16) unsigned short Minvh[32*SR32], Minvl[32*SR32];
    __shared__ __align__(16) unsigned short Quuh[32*SR32],  Quul[32*SR32];
    __shared__ __align__(16) unsigned short Rth[64*SR32];
    __shared__ __align__(16) float qh[96];
    __shared__ __align__(16) float gv[64];
    __shared__ __align__(16) float hbuf[32];
    __shared__ __align__(16) float c1l[64];
    __shared__ __align__(16) float vl[64];
    __shared__ __align__(16) float kkl[32];
    __shared__ __align__(16) float x0l[64];
    __shared__ float wpart[8];
    __shared__ float wAcc;

    const int tid = threadIdx.x;
    const int b   = blockIdx.x;
    const int w   = tid >> 6;        // wave 0..7
    const int lm  = tid & 15;        // fragment row/col
    const int lk  = (tid & 63) >> 4; // fragment k-group 0..3

    const float* Qg = Qg_ + (size_t)b*T*NSC*NSC;
    const float* pg = pg_ + (size_t)b*T*NSC;
    const float* Ag = Ag_ + (size_t)b*NS*NS;
    const float* Bg = Bg_ + (size_t)b*NS*NC;
    float* KtG = g_KtG + (size_t)b*T*NS*NC;
    float* kkG = g_kkG + (size_t)b*T*NC;

    // ---- init: F -> bf16 hi/lo transposed; V = 0 (fp32 + bf16)
    for (int e = tid; e < 96*64; e += 512) {
        const int j = e >> 6, s = e & 63;
        const float x = (j < 64) ? Ag[s*64 + j] : Bg[s*32 + (j-64)];
        const unsigned short h = f2bf(x);
        Fth[j*BROW + s] = h;
        Ftl[j*BROW + s] = f2bf(x - bf2f(h));
    }
    for (int e = tid; e < 64*BROW; e += 512) { Vbh[e] = 0; Vbl[e] = 0; }
    for (int e = tid; e < 64*68; e += 512) ((float*)V)[e] = 0.f;
    if (tid < 64) { c1l[tid] = c1g_[b*64+tid]; vl[tid] = 0.f; x0l[tid] = x0g_[b*64+tid]; }
    if (tid == 0) wAcc = 0.f;
    __syncthreads();

    // GJ thread roles
    const int wq  = tid >> 4;
    const int gjq = tid & 15, gj0 = gjq * 4;

    // P2 tile schedule: waves 0-3: 4 tiles, waves 4-7: 3 tiles (28 total)
    const int p2s = (w < 4) ? w*4 : 16 + (w-4)*3;
    const int p2n = (w < 4) ? 4 : 3;

    for (int t = T-1; t >= 0; --t) {
        const float* Qt = Qg + (size_t)t*NSC*NSC;
        const float* pt = pg + (size_t)t*NSC;

        // ---- Qt prefetch for this wave's P2 tiles (issued early, used in P2)
        f32x4 qt0, qt1, qt2, qt3;
        {
            int i0, j0, os;
            p2geom(p2s+0, i0, j0, os);
            const float* s0p = Qt + (size_t)(i0 + lk*4)*96 + j0 + lm;
            qt0[0]=s0p[0]; qt0[1]=s0p[96]; qt0[2]=s0p[192]; qt0[3]=s0p[288];
            p2geom(p2s+1, i0, j0, os);
            const float* s1p = Qt + (size_t)(i0 + lk*4)*96 + j0 + lm;
            qt1[0]=s1p[0]; qt1[1]=s1p[96]; qt1[2]=s1p[192]; qt1[3]=s1p[288];
            p2geom(p2s+2, i0, j0, os);
            const float* s2p = Qt + (size_t)(i0 + lk*4)*96 + j0 + lm;
            qt2[0]=s2p[0]; qt2[1]=s2p[96]; qt2[2]=s2p[192]; qt2[3]=s2p[288];
            if (p2n == 4) {
                p2geom(p2s+3, i0, j0, os);
                const float* s3p = Qt + (size_t)(i0 + lk*4)*96 + j0 + lm;
                qt3[0]=s3p[0]; qt3[1]=s3p[96]; qt3[2]=s3p[192]; qt3[3]=s3p[288];
            } else { qt3 = qt0; }
        }

        // ---- P0a (all 512): gv[l] = V[l]*c1 + v[l] (8 thr/output, butterfly);
        //      wAcc c1-term partials -> wpart[wave]
        {
            const int l = tid >> 3, g = tid & 7;
            const int k0 = g * 8;
            float d = dot4(*(const float4*)&V[l][k0],   *(const float4*)&c1l[k0])
                    + dot4(*(const float4*)&V[l][k0+4], *(const float4*)&c1l[k0+4]);
            d += __shfl_xor(d, 1); d += __shfl_xor(d, 2); d += __shfl_xor(d, 4);
            if (g == 0) gv[l] = d + vl[l];
            float term = (g == 0) ? c1l[l]*(0.5f*d + vl[l]) : 0.f;
            term += __shfl_xor(term, 8); term += __shfl_xor(term, 16); term += __shfl_xor(term, 32);
            if ((tid & 63) == 0) wpart[w] = term;
        }
        __syncthreads();

        // ---- P0b (384 thr): qh[j] = pt[j] + sum_s F[s][j]*gv[s] via bf16 Ft rows
        if (tid < 384) {
            const int j = tid >> 2, g = tid & 3;
            const int s0 = g * 16;
            const bf16x8 h0 = *(const bf16x8*)&Fth[j*BROW + s0];
            const bf16x8 l0 = *(const bf16x8*)&Ftl[j*BROW + s0];
            const bf16x8 h1 = *(const bf16x8*)&Fth[j*BROW + s0 + 8];
            const bf16x8 l1 = *(const bf16x8*)&Ftl[j*BROW + s0 + 8];
            float s = 0.f;
            #pragma unroll
            for (int i = 0; i < 8; ++i) {
                s = fmaf(bf2f((unsigned short)h0[i]) + bf2f((unsigned short)l0[i]), gv[s0+i],   s);
                s = fmaf(bf2f((unsigned short)h1[i]) + bf2f((unsigned short)l1[i]), gv[s0+8+i], s);
            }
            s += __shfl_xor(s, 1); s += __shfl_xor(s, 2);
            if (g == 0) qh[j] = pt[j] + s;
        } else if (tid == 448) {
            float s = 0.f;
            #pragma unroll
            for (int i = 0; i < 8; ++i) s += wpart[i];
            wAcc += s;
        }
        __syncthreads();

        // ---- P1 (MFMA): W = V*F, 24 tiles over ALL 8 waves (3 each)
        {
            const int st = w * 3;
            P1TILE(st+0)
            P1TILE(st+1)
            P1TILE(st+2)
        }
        __syncthreads();

        // ---- P2 (MFMA): Qh = Qt + F'W; 28 tiles over all 8 waves.
        //      Quu tiles stage GJ block-0 pivot rows/cols; identity half below.
        P2TILE(qt0, p2s+0)
        P2TILE(qt1, p2s+1)
        P2TILE(qt2, p2s+2)
        if (p2n == 4) { P2TILE(qt3, p2s+3) }
        if (tid < 64) {   // identity half of GJ block-0 pivot rows
            const int rr = tid >> 5, cc2 = tid & 31;
            prow2[0][rr][32 + cc2] = (cc2 == rr) ? 1.f : 0.f;
        }
        __syncthreads();

        // ---- P3: 2x2-blocked Gauss-Jordan of Quu, matrix-in-registers,
        //      1 barrier per 2 pivots (16 total). Exact block elimination.
        //      Epilogue: Minv registers -> Maug cols 32:64 (fp32) + bf16 hi/lo.
        {
            float4 m;
            if (gjq < 8) m = *(const float4*)&Maug[wq][gj0];
            else {
                const int base = gj0 - 32;
                m.x = (base+0==wq)?1.f:0.f; m.y = (base+1==wq)?1.f:0.f;
                m.z = (base+2==wq)?1.f:0.f; m.w = (base+3==wq)?1.f:0.f;
            }
            #pragma unroll
            for (int blk = 0; blk < 16; ++blk) {
                const int k = blk*2;
                const int par = blk & 1, nxt = par ^ 1;
                const float a  = prow2[par][0][k],  bq = prow2[par][0][k+1];
                const float cc = prow2[par][1][k],  d  = prow2[par][1][k+1];
                const float idet = 1.0f / fmaf(a, d, -bq*cc);
                const float4 r0 = *(const float4*)&prow2[par][0][gj0];
                const float4 r1 = *(const float4*)&prow2[par][1][gj0];
                if (wq == k) {
                    m.x = (d*r0.x - bq*r1.x)*idet;
                    m.y = (d*r0.y - bq*r1.y)*idet;
                    m.z = (d*r0.z - bq*r1.z)*idet;
                    m.w = (d*r0.w - bq*r1.w)*idet;
                } else if (wq == k+1) {
                    m.x = (a*r1.x - cc*r0.x)*idet;
                    m.y = (a*r1.y - cc*r0.y)*idet;
                    m.z = (a*r1.z - cc*r0.z)*idet;
                    m.w = (a*r1.w - cc*r0.w)*idet;
                } else {
                    const float C0 = pfac2[par][0][wq], C1 = pfac2[par][1][wq];
                    const float E0 = (C0*d - C1*cc)*idet;
                    const float E1 = (C1*a - C0*bq)*idet;
                    m.x = fmaf(-E0, r0.x, fmaf(-E1, r1.x, m.x));
                    m.y = fmaf(-E0, r0.y, fmaf(-E1, r1.y, m.y));
                    m.z = fmaf(-E0, r0.z, fmaf(-E1, r1.z, m.z));
                    m.w = fmaf(-E0, r0.w, fmaf(-E1, r1.w, m.w));
                }
                if (blk < 15) {
                    if (wq == k+2)      *(float4*)&prow2[nxt][0][gj0] = m;
                    else if (wq == k+3) *(float4*)&prow2[nxt][1][gj0] = m;
                    if (gjq == ((k+2) >> 2)) {
                        pfac2[nxt][0][wq] = COMP(m, (k+2)&3);
                        pfac2[nxt][1][wq] = COMP(m, (k+3)&3);
                    }
                }
                __syncthreads();
            }
            if (gjq >= 8) {
                *(float4*)&Maug[wq][gj0] = m;   // fp32 Minv at cols 32:64 (kk tail)
                ushort4 hv, lv;
                hv.x = f2bf(m.x); lv.x = f2bf(m.x - bf2f(hv.x));
                hv.y = f2bf(m.y); lv.y = f2bf(m.y - bf2f(hv.y));
                hv.z = f2bf(m.z); lv.z = f2bf(m.z - bf2f(hv.z));
                hv.w = f2bf(m.w); lv.w = f2bf(m.w - bf2f(hv.w));
                const int u_ = gj0 - 32;
                *(ushort4*)&Minvh[wq*SR32 + u_] = hv;
                *(ushort4*)&Minvl[wq*SR32 + u_] = lv;
            }
            __syncthreads();
        }

        // ---- P4 (MFMA): K = -Qxu*Minv^T; 8 tiles, 1/wave. kk = -Minv*qu (tail).
        {
            const int i0 = (w & 3)*16, u0 = (w >> 2)*16;
            const int ch = lk*8;
            f32x4 c = {0.f,0.f,0.f,0.f};
            const bf16x8 ah = *(const bf16x8*)&Qxuh[(i0+lm)*SR32 + ch];
            const bf16x8 al = *(const bf16x8*)&Qxul[(i0+lm)*SR32 + ch];
            const bf16x8 bh = *(const bf16x8*)&Minvh[(u0+lm)*SR32 + ch];
            const bf16x8 bl = *(const bf16x8*)&Minvl[(u0+lm)*SR32 + ch];
            c = __builtin_amdgcn_mfma_f32_16x16x32_bf16(ah, bh, c, 0, 0, 0);
            c = __builtin_amdgcn_mfma_f32_16x16x32_bf16(ah, bl, c, 0, 0, 0);
            c = __builtin_amdgcn_mfma_f32_16x16x32_bf16(al, bh, c, 0, 0, 0);
            #pragma unroll
            for (int r = 0; r < 4; ++r) {
                const int i_ = i0 + lk*4 + r, u_ = u0 + lm;
                const float kv = -c[r];
                KtG[(size_t)t*2048 + i_*32 + u_] = kv;
                const unsigned short h = f2bf(kv);
                Kth[i_*SR32 + u_] = h;
                Ktl[i_*SR32 + u_] = f2bf(kv - bf2f(h));
            }
            if (tid < 32) {
                float ka = 0.f;
                #pragma unroll
                for (int w4 = 0; w4 < 8; ++w4)
                    ka -= dot4(*(const float4*)&Maug[tid][32+w4*4], *(const float4*)&qh[64+w4*4]);
                kkl[tid] = ka;
                kkG[t*32 + tid] = ka;
            }
        }
        __syncthreads();

        // ---- P5 (MFMA): Rt[j][u] = Qxu[j][u] + (Kt*Quu)[j][u]; 8 tiles, hi-only out.
        //      hbuf = qu + Quu*kk (tail).
        {
            const int j0 = (w & 3)*16, u0 = (w >> 2)*16;
            const int ch = lk*8;
            f32x4 c;
            #pragma unroll
            for (int r = 0; r < 4; ++r) c[r] = Qxu[j0 + lk*4 + r][u0 + lm];
            const bf16x8 ah = *(const bf16x8*)&Kth[(j0+lm)*SR32 + ch];
            const bf16x8 al = *(const bf16x8*)&Ktl[(j0+lm)*SR32 + ch];
            const bf16x8 bh = *(const bf16x8*)&Quuh[(u0+lm)*SR32 + ch];
            const bf16x8 bl = *(const bf16x8*)&Quul[(u0+lm)*SR32 + ch];
            c = __builtin_amdgcn_mfma_f32_16x16x32_bf16(ah, bh, c, 0, 0, 0);
            c = __builtin_amdgcn_mfma_f32_16x16x32_bf16(ah, bl, c, 0, 0, 0);
            c = __builtin_amdgcn_mfma_f32_16x16x32_bf16(al, bh, c, 0, 0, 0);
            #pragma unroll
            for (int r = 0; r < 4; ++r)
                Rth[(j0 + lk*4 + r)*SR32 + u0 + lm] = f2bf(c[r]);
            if (tid < 32) {
                float h = qh[64+tid];
                #pragma unroll
                for (int w4 = 0; w4 < 8; ++w4)
                    h += dot4(*(const float4*)&QuuC[tid][w4*4], *(const float4*)&kkl[w4*4]);
                hbuf[tid] = h;
            }
        }
        __syncthreads();

        // ---- P6 (MFMA): V <- Qxx + Qxu*K + K'Rt; 16 tiles, 2/wave, in-place V.
        #pragma unroll
        for (int half = 0; half < 2; ++half) {
            const int tx = w + half*8;
            const int i0 = (tx & 3)*16, j0 = (tx >> 2)*16;
            const int ch = lk*8;
            f32x4 c;
            #pragma unroll
            for (int r = 0; r < 4; ++r) c[r] = V[i0 + lk*4 + r][j0 + lm];
            const bf16x8 ah  = *(const bf16x8*)&Qxuh[(i0+lm)*SR32 + ch];
            const bf16x8 al  = *(const bf16x8*)&Qxul[(i0+lm)*SR32 + ch];
            const bf16x8 bh  = *(const bf16x8*)&Kth[(j0+lm)*SR32 + ch];
            const bf16x8 bl  = *(const bf16x8*)&Ktl[(j0+lm)*SR32 + ch];
            const bf16x8 a2h = *(const bf16x8*)&Kth[(i0+lm)*SR32 + ch];
            const bf16x8 b2h = *(const bf16x8*)&Rth[(j0+lm)*SR32 + ch];
            c = __builtin_amdgcn_mfma_f32_16x16x32_bf16(ah,  bh,  c, 0, 0, 0);
            c = __builtin_amdgcn_mfma_f32_16x16x32_bf16(ah,  bl,  c, 0, 0, 0);
            c = __builtin_amdgcn_mfma_f32_16x16x32_bf16(al,  bh,  c, 0, 0, 0);
            c = __builtin_amdgcn_mfma_f32_16x16x32_bf16(a2h, b2h, c, 0, 0, 0);
            #pragma unroll
            for (int r = 0; r < 4; ++r) V[i0 + lk*4 + r][j0 + lm] = c[r];
        }
        __syncthreads();

        // ---- symmetrize V + bf16 convert (256 thr); vn (256-319); wAcc (320-351)
        if (tid < 256) {
            const int a = tid >> 4, bq = tid & 15;
            if (a < bq) {
                float4 t1[4], t2[4];
                #pragma unroll
                for (int r = 0; r < 4; ++r) {
                    t1[r] = *(const float4*)&V[4*a+r][4*bq];
                    t2[r] = *(const float4*)&V[4*bq+r][4*a];
                }
                #pragma unroll
                for (int r = 0; r < 4; ++r) {
                    float4 o, p;
                    o.x = 0.5f*(COMP(t1[r],0)+COMP(t2[0],r));
                    o.y = 0.5f*(COMP(t1[r],1)+COMP(t2[1],r));
                    o.z = 0.5f*(COMP(t1[r],2)+COMP(t2[2],r));
                    o.w = 0.5f*(COMP(t1[r],3)+COMP(t2[3],r));
                    p.x = 0.5f*(COMP(t2[r],0)+COMP(t1[0],r));
                    p.y = 0.5f*(COMP(t2[r],1)+COMP(t1[1],r));
                    p.z = 0.5f*(COMP(t2[r],2)+COMP(t1[2],r));
                    p.w = 0.5f*(COMP(t2[r],3)+COMP(t1[3],r));
                    *(float4*)&V[4*a+r][4*bq] = o;
                    *(float4*)&V[4*bq+r][4*a] = p;
                    ushort4 oh, ol, ph, pl;
                    oh.x=f2bf(o.x); ol.x=f2bf(o.x-bf2f(oh.x));
                    oh.y=f2bf(o.y); ol.y=f2bf(o.y-bf2f(oh.y));
                    oh.z=f2bf(o.z); ol.z=f2bf(o.z-bf2f(oh.z));
                    oh.w=f2bf(o.w); ol.w=f2bf(o.w-bf2f(oh.w));
                    ph.x=f2bf(p.x); pl.x=f2bf(p.x-bf2f(ph.x));
                    ph.y=f2bf(p.y); pl.y=f2bf(p.y-bf2f(ph.y));
                    ph.z=f2bf(p.z); pl.z=f2bf(p.z-bf2f(ph.z));
                    ph.w=f2bf(p.w); pl.w=f2bf(p.w-bf2f(ph.w));
                    *(ushort4*)&Vbh[(4*a+r)*BROW + 4*bq] = oh;
                    *(ushort4*)&Vbl[(4*a+r)*BROW + 4*bq] = ol;
                    *(ushort4*)&Vbh[(4*bq+r)*BROW + 4*a] = ph;
                    *(ushort4*)&Vbl[(4*bq+r)*BROW + 4*a] = pl;
                }
            } else if (a == bq) {
                float4 t1[4];
                #pragma unroll
                for (int r = 0; r < 4; ++r) t1[r] = *(const float4*)&V[4*a+r][4*a];
                #pragma unroll
                for (int r = 0; r < 4; ++r) {
                    float4 o;
                    o.x = 0.5f*(COMP(t1[r],0)+COMP(t1[0],r));
                    o.y = 0.5f*(COMP(t1[r],1)+COMP(t1[1],r));
                    o.z = 0.5f*(COMP(t1[r],2)+COMP(t1[2],r));
                    o.w = 0.5f*(COMP(t1[r],3)+COMP(t1[3],r));
                    *(float4*)&V[4*a+r][4*a] = o;
                    ushort4 oh, ol;
                    oh.x=f2bf(o.x); ol.x=f2bf(o.x-bf2f(oh.x));
                    oh.y=f2bf(o.y); ol.y=f2bf(o.y-bf2f(oh.y));
                    oh.z=f2bf(o.z); ol.z=f2bf(o.z-bf2f(oh.z));
                    oh.w=f2bf(o.w); ol.w=f2bf(o.w-bf2f(oh.w));
                    *(ushort4*)&Vbh[(4*a+r)*BROW + 4*a] = oh;
                    *(ushort4*)&Vbl[(4*a+r)*BROW + 4*a] = ol;
                }
            }
        } else if (tid < 320) {
            const int l = tid - 256;
            float vv = qh[l];
            #pragma unroll
            for (int u4 = 0; u4 < 8; ++u4)
                vv += dot4(*(const float4*)&Qxu[l][u4*4], *(const float4*)&kkl[u4*4]);
            #pragma unroll
            for (int cg = 0; cg < 4; ++cg) {
                const bf16x8 h8 = *(const bf16x8*)&Kth[l*SR32 + cg*8];
                const bf16x8 l8 = *(const bf16x8*)&Ktl[l*SR32 + cg*8];
                #pragma unroll
                for (int i = 0; i < 8; ++i)
                    vv = fmaf(bf2f((unsigned short)h8[i]) + bf2f((unsigned short)l8[i]),
                              hbuf[cg*8+i], vv);
            }
            vl[l] = vv;
        } else if (tid < 352) {
            const int u = tid - 320;
            float r = kkl[u]*(hbuf[u] + qh[64+u]);
            r += __shfl_xor(r,16); r += __shfl_xor(r,8); r += __shfl_xor(r,4);
            r += __shfl_xor(r,2);  r += __shfl_xor(r,1);
            if (u == 0) wAcc += 0.5f*r;
        }
        __syncthreads();
    }

    // ---- cost[b] = wAcc + 0.5*x0'V0 x0 + v0'x0
    if (tid < 64) {
        float rd = 0.f;
        #pragma unroll
        for (int k4 = 0; k4 < 16; ++k4)
            rd += dot4(*(const float4*)&V[tid][k4*4], *(const float4*)&x0l[k4*4]);
        float ps = x0l[tid]*(0.5f*rd + vl[tid]);
        ps += __shfl_xor(ps,32); ps += __shfl_xor(ps,16); ps += __shfl_xor(ps,8);
        ps += __shfl_xor(ps,4);  ps += __shfl_xor(ps,2);  ps += __shfl_xor(ps,1);
        if (tid == 0) outc[b] = wAcc + ps;
    }
}

// ---------------------------------------------------------------------------
// Forward rollout (unchanged): 256 threads per batch; split dot products
// with shfl_xor reduction; K(t+1) reg-prefetched.
// ---------------------------------------------------------------------------
__global__ __launch_bounds__(256)
void lqr_fwd(const float* __restrict__ Ag_, const float* __restrict__ Bg_,
             const float* __restrict__ c1g_, const float* __restrict__ x0g_,
             float* __restrict__ outx, float* __restrict__ outu)
{
    __shared__ __align__(16) float At[64][68];
    __shared__ __align__(16) float Bt[32][68];
    __shared__ __align__(16) float KtL[64][36];
    __shared__ float xl[64], ul[32], cl[64], kl[32], xnb[64];

    const int tid = threadIdx.x;
    const int b = blockIdx.x;

    const float* KtG = g_KtG + (size_t)b*T*NS*NC;
    const float* kkG = g_kkG + (size_t)b*T*NC;

    for (int e = tid; e < NS*NS; e += 256) At[e&63][e>>6] = Ag_[(size_t)b*4096 + e];
    for (int e = tid; e < NS*NC; e += 256) Bt[e&31][e>>5] = Bg_[(size_t)b*2048 + e];
    if (tid < 64) { xl[tid] = x0g_[b*64 + tid]; cl[tid] = c1g_[b*64 + tid]; }

    {
        const int i1 = tid*4, i2 = 1024 + tid*4;
        const float4 a = *(const float4*)&KtG[i1];
        const float4 c = *(const float4*)&KtG[i2];
        *(float4*)&KtL[i1>>5][i1&31] = a;
        *(float4*)&KtL[i2>>5][i2&31] = c;
        if (tid < 32) kl[tid] = kkG[tid];
    }
    __syncthreads();

    float4 g0, g1; float kn = 0.f;
    for (int t = 0; t < T; ++t) {
        if (t+1 < T) {
            g0 = *(const float4*)&KtG[(size_t)(t+1)*2048 + tid*4];
            g1 = *(const float4*)&KtG[(size_t)(t+1)*2048 + 1024 + tid*4];
            if (tid < 32) kn = kkG[(t+1)*32 + tid];
        }

        if (tid < 64) outx[((size_t)b*T + t)*64 + tid] = xl[tid];
        if (tid < 128) {
            const int u = tid >> 2, sp = tid & 3, s0 = sp*16;
            float r = 0.f;
            #pragma unroll
            for (int i = 0; i < 16; ++i) r = fmaf(KtL[s0+i][u], xl[s0+i], r);
            r += __shfl_xor(r, 1); r += __shfl_xor(r, 2);
            if (sp == 0) {
                const float uu = r + kl[u];
                ul[u] = uu;
                outu[((size_t)b*T + t)*32 + u] = uu;
            }
        }
        __syncthreads();

        {
            const int o = tid >> 2, sp = tid & 3;
            float r = 0.f;
            #pragma unroll
            for (int i = 0; i < 16; ++i) { const int j = sp*16 + i; r = fmaf(At[j][o], xl[j], r); }
            #pragma unroll
            for (int i = 0; i < 8; ++i)  { const int w2 = sp*8 + i; r = fmaf(Bt[w2][o], ul[w2], r); }
            r += __shfl_xor(r, 1); r += __shfl_xor(r, 2);
            if (sp == 0) xnb[o] = r + cl[o];
        }
        __syncthreads();

        if (tid < 64) xl[tid] = xnb[tid];
        if (t+1 < T) {
            const int i1 = tid*4, i2 = 1024 + tid*4;
            *(float4*)&KtL[i1>>5][i1&31] = g0;
            *(float4*)&KtL[i2>>5][i2&31] = g1;
            if (tid < 32) kl[tid] = kn;
        }
        __syncthreads();
    }
}

// ---------------------------------------------------------------------------
extern "C" void kernel_launch(void* const* d_in, const int* in_sizes, int n_in,
                              void* d_out, int out_size, void* d_ws, size_t ws_size,
                              hipStream_t stream)
{
    const float* Q  = (const float*)d_in[0];
    const float* p  = (const float*)d_in[1];
    const float* A  = (const float*)d_in[2];
    const float* B  = (const float*)d_in[3];
    const float* c1 = (const float*)d_in[4];
    const float* x0 = (const float*)d_in[5];

    float* outx = (float*)d_out;                       // (NB,T,NS)
    float* outu = outx + (size_t)NB*T*NS;              // (NB,T,NC)
    float* outc = outu + (size_t)NB*T*NC;              // (NB,)

    lqr_bwd<<<NB, 512, 0, stream>>>(Q, p, A, B, c1, x0, outc);
    lqr_fwd<<<NB, 256, 0, stream>>>(A, B, c1, x0, outx, outu);
}